// Round 1
// baseline (17944.006 us; speedup 1.0000x reference)
//
#include <hip/hip_runtime.h>
#include <math.h>

// Problem constants
#define VOCAB 32000
#define EDIM  512
#define HDIM  512
#define NLAYERS 4
#define BATCH 32
#define TSTEPS 64
#define G4 2048  // 4*HDIM

typedef __attribute__((ext_vector_type(8))) short bf16x8;
typedef __attribute__((ext_vector_type(4))) float f32x4;

static __device__ __forceinline__ unsigned short f2b(float f) {
    union { float f; unsigned u; } v; v.f = f;
    unsigned r = (v.u + 0x7FFFu + ((v.u >> 16) & 1u)) >> 16;
    return (unsigned short)r;
}

static __device__ __forceinline__ float sigf(float x) {
    return 1.0f / (1.0f + __expf(-x));
}

// ---------------- embedding gather: seq[t][b][e] = emb[dec[b][t]][e] ----------------
__global__ void k_embed(const float* __restrict__ emb, const int* __restrict__ dec,
                        float* __restrict__ seqF, unsigned short* __restrict__ seqB) {
    int tb = blockIdx.x;           // t*BATCH + b
    int t = tb >> 5, b = tb & 31;
    int tok = dec[b * TSTEPS + t];
    const float* src = emb + (size_t)tok * EDIM;
    float* dst = seqF + (size_t)tb * EDIM;
    unsigned short* dstb = seqB + (size_t)tb * EDIM;
    for (int e = threadIdx.x; e < EDIM; e += blockDim.x) {
        float v = src[e];
        dst[e] = v;
        dstb[e] = f2b(v);
    }
}

// ---------------- fp32 -> bf16 convert (vectorized) ----------------
__global__ void k_cvt4(const float4* __restrict__ src, ushort4* __restrict__ dst, long n4) {
    long i = blockIdx.x * (long)blockDim.x + threadIdx.x;
    long stride = (long)gridDim.x * blockDim.x;
    for (; i < n4; i += stride) {
        float4 f = src[i];
        ushort4 u;
        u.x = f2b(f.x); u.y = f2b(f.y); u.z = f2b(f.z); u.w = f2b(f.w);
        dst[i] = u;
    }
}

// ---------------- plain f32 copy ----------------
__global__ void k_copyf(const float* __restrict__ src, float* __restrict__ dst, int n) {
    int i = blockIdx.x * blockDim.x + threadIdx.x;
    if (i < n) dst[i] = src[i];
}

// ---------------- bf16 MFMA GEMM: C[M,N] = A[M,K] @ Bm[N,K]^T + bias1 + bias2 ----------------
// M=2048 (t*B+b rows), N=2048 (gate dims), K=512. Tile 64x64 per block, 4 waves of 32x32.
__global__ __launch_bounds__(256) void k_gemm_bias(
    const unsigned short* __restrict__ A, const unsigned short* __restrict__ Bm,
    const float* __restrict__ bias1, const float* __restrict__ bias2,
    float* __restrict__ C) {
    const int M = 2048, N = 2048, K = 512;
    int mt = blockIdx.x & 31;           // 32 m-tiles
    int nt = blockIdx.x >> 5;           // 32 n-tiles
    int m0 = mt * 64, n0 = nt * 64;
    int wave = threadIdx.x >> 6;
    int lane = threadIdx.x & 63;
    int wm = m0 + (wave >> 1) * 32;
    int wn = n0 + (wave & 1) * 32;
    int lm = lane & 15;                 // row/col within 16-frag
    int lk = 8 * (lane >> 4);           // k offset within 32-chunk

    f32x4 acc[2][2];
    #pragma unroll
    for (int i = 0; i < 2; ++i)
        #pragma unroll
        for (int j = 0; j < 2; ++j) acc[i][j] = (f32x4)(0.0f);

    for (int k0 = 0; k0 < K; k0 += 32) {
        bf16x8 a[2], b[2];
        #pragma unroll
        for (int mi = 0; mi < 2; ++mi)
            a[mi] = *(const bf16x8*)(A + (size_t)(wm + mi * 16 + lm) * K + k0 + lk);
        #pragma unroll
        for (int ni = 0; ni < 2; ++ni)
            b[ni] = *(const bf16x8*)(Bm + (size_t)(wn + ni * 16 + lm) * K + k0 + lk);
        #pragma unroll
        for (int mi = 0; mi < 2; ++mi)
            #pragma unroll
            for (int ni = 0; ni < 2; ++ni)
                acc[mi][ni] = __builtin_amdgcn_mfma_f32_16x16x32_bf16(a[mi], b[ni], acc[mi][ni], 0, 0, 0);
    }
    // C/D layout: col = lane&15, row = (lane>>4)*4 + r
    #pragma unroll
    for (int mi = 0; mi < 2; ++mi) {
        #pragma unroll
        for (int ni = 0; ni < 2; ++ni) {
            int col = wn + ni * 16 + lm;
            float bsum = bias1[col] + bias2[col];
            #pragma unroll
            for (int r = 0; r < 4; ++r) {
                int row = wm + mi * 16 + (lane >> 4) * 4 + r;
                C[(size_t)row * N + col] = acc[mi][ni][r] + bsum;
            }
        }
    }
}

// ---------------- LSTM recurrence step (fp32 vector) ----------------
// gates[b][j] = gin[b][j] + sum_h h_in[b][h] * whh[j][h];  cell update; residual out.
// 64 blocks x 256 threads; thread = (b = tid>>3, dslot = tid&7); d = blockIdx*8+dslot.
__global__ __launch_bounds__(256) void k_lstm_step(
    const float* __restrict__ gin,      // [B][4H] slice at time t
    const float* __restrict__ whh,      // [4H][H] layer slice
    const float* __restrict__ inp,      // [B][H] residual input
    const float* __restrict__ h_in,     // [B][H]
    float* __restrict__ h_out,          // [B][H]
    float* __restrict__ c_st,           // [B][H] in-place (each (b,d) owned by one thread)
    float* __restrict__ outF,           // [B][H]
    unsigned short* __restrict__ outB) {
    const int dslot = threadIdx.x & 7;
    const int b = threadIdx.x >> 3;
    const int d = blockIdx.x * 8 + dslot;

    const float4* hv = (const float4*)(h_in + (size_t)b * HDIM);
    const float4* w0 = (const float4*)(whh + ((size_t)0 * HDIM + d) * HDIM);
    const float4* w1 = (const float4*)(whh + ((size_t)1 * HDIM + d) * HDIM);
    const float4* w2 = (const float4*)(whh + ((size_t)2 * HDIM + d) * HDIM);
    const float4* w3 = (const float4*)(whh + ((size_t)3 * HDIM + d) * HDIM);

    float s0 = 0.f, s1 = 0.f, s2 = 0.f, s3 = 0.f;
    #pragma unroll 4
    for (int k = 0; k < HDIM / 4; ++k) {
        float4 hh = hv[k];
        float4 a0 = w0[k], a1 = w1[k], a2 = w2[k], a3 = w3[k];
        s0 += hh.x * a0.x + hh.y * a0.y + hh.z * a0.z + hh.w * a0.w;
        s1 += hh.x * a1.x + hh.y * a1.y + hh.z * a1.z + hh.w * a1.w;
        s2 += hh.x * a2.x + hh.y * a2.y + hh.z * a2.z + hh.w * a2.w;
        s3 += hh.x * a3.x + hh.y * a3.y + hh.z * a3.z + hh.w * a3.w;
    }
    float gi = gin[b * G4 + 0 * HDIM + d] + s0;
    float gf = gin[b * G4 + 1 * HDIM + d] + s1;
    float gg = gin[b * G4 + 2 * HDIM + d] + s2;
    float go = gin[b * G4 + 3 * HDIM + d] + s3;

    float c_old = c_st[b * HDIM + d];
    float ci = sigf(gf) * c_old + sigf(gi) * tanhf(gg);
    float hi = sigf(go) * tanhf(ci);
    float o = hi + inp[b * HDIM + d];   // residual (E == H)

    c_st[b * HDIM + d] = ci;
    h_out[b * HDIM + d] = hi;
    outF[b * HDIM + d] = o;
    outB[b * HDIM + d] = f2b(o);
}

// ---------------- fused classifier + log_softmax over T ----------------
// Block: b = blockIdx&31, vtile = blockIdx>>5 (128 v per block). 4 waves, each 64t x 32v.
// b_cls omitted: constant across t, cancels exactly in log_softmax(axis=T).
__global__ __launch_bounds__(256) void k_cls(
    const unsigned short* __restrict__ A,   // seq bf16, rows t*B+b, [.,512]
    const unsigned short* __restrict__ W,   // W_cls bf16 [V][512]
    float* __restrict__ out) {              // [B][T][V]
    int b = blockIdx.x & 31;
    int vt = blockIdx.x >> 5;
    int v0 = vt * 128;
    int wave = threadIdx.x >> 6;
    int lane = threadIdx.x & 63;
    int wn0 = v0 + wave * 32;
    int lm = lane & 15;
    int lk = 8 * (lane >> 4);

    f32x4 acc[4][2];
    #pragma unroll
    for (int i = 0; i < 4; ++i)
        #pragma unroll
        for (int j = 0; j < 2; ++j) acc[i][j] = (f32x4)(0.0f);

    for (int k0 = 0; k0 < HDIM; k0 += 32) {
        bf16x8 a[4], bb[2];
        #pragma unroll
        for (int mi = 0; mi < 4; ++mi) {
            int t = mi * 16 + lm;
            a[mi] = *(const bf16x8*)(A + ((size_t)(t * BATCH + b)) * HDIM + k0 + lk);
        }
        #pragma unroll
        for (int ni = 0; ni < 2; ++ni) {
            int v = wn0 + ni * 16 + lm;
            bb[ni] = *(const bf16x8*)(W + (size_t)v * HDIM + k0 + lk);
        }
        #pragma unroll
        for (int mi = 0; mi < 4; ++mi)
            #pragma unroll
            for (int ni = 0; ni < 2; ++ni)
                acc[mi][ni] = __builtin_amdgcn_mfma_f32_16x16x32_bf16(a[mi], bb[ni], acc[mi][ni], 0, 0, 0);
    }

    // Per column v: logsumexp over all 64 t (rows). Rows live in regs r, frags mi,
    // and lane groups lane>>4 (xor masks 16, 32).
    #pragma unroll
    for (int ni = 0; ni < 2; ++ni) {
        float m = -1e30f;
        #pragma unroll
        for (int mi = 0; mi < 4; ++mi)
            #pragma unroll
            for (int r = 0; r < 4; ++r) m = fmaxf(m, acc[mi][ni][r]);
        m = fmaxf(m, __shfl_xor(m, 16));
        m = fmaxf(m, __shfl_xor(m, 32));
        float s = 0.f;
        #pragma unroll
        for (int mi = 0; mi < 4; ++mi)
            #pragma unroll
            for (int r = 0; r < 4; ++r) s += expf(acc[mi][ni][r] - m);
        s += __shfl_xor(s, 16);
        s += __shfl_xor(s, 32);
        float logZ = m + logf(s);
        int v = wn0 + ni * 16 + lm;
        #pragma unroll
        for (int mi = 0; mi < 4; ++mi) {
            #pragma unroll
            for (int r = 0; r < 4; ++r) {
                int t = mi * 16 + (lane >> 4) * 4 + r;
                out[((size_t)b * TSTEPS + t) * VOCAB + v] = acc[mi][ni][r] - logZ;
            }
        }
    }
}

extern "C" void kernel_launch(void* const* d_in, const int* in_sizes, int n_in,
                              void* d_out, int out_size, void* d_ws, size_t ws_size,
                              hipStream_t stream) {
    // inputs per setup_inputs() order; context (d_in[0]) and b_cls (d_in[10]) unused
    const int*   dec   = (const int*)d_in[1];
    const float* h0    = (const float*)d_in[2];
    const float* c0    = (const float*)d_in[3];
    const float* emb   = (const float*)d_in[4];
    const float* W_ih  = (const float*)d_in[5];
    const float* W_hh  = (const float*)d_in[6];
    const float* b_ih  = (const float*)d_in[7];
    const float* b_hh  = (const float*)d_in[8];
    const float* W_cls = (const float*)d_in[9];

    const int LBH = NLAYERS * BATCH * HDIM;         // 65536
    const size_t BTV = (size_t)BATCH * TSTEPS * VOCAB;

    char* ws = (char*)d_ws;
    size_t off = 0;
    auto alloc = [&](size_t bytes) -> void* {
        void* p = ws + off;
        off = (off + bytes + 255) & ~(size_t)255;
        return p;
    };
    float* seqF0 = (float*)alloc((size_t)TSTEPS * BATCH * HDIM * 4);
    float* seqF1 = (float*)alloc((size_t)TSTEPS * BATCH * HDIM * 4);
    unsigned short* seqB0 = (unsigned short*)alloc((size_t)TSTEPS * BATCH * HDIM * 2);
    unsigned short* seqB1 = (unsigned short*)alloc((size_t)TSTEPS * BATCH * HDIM * 2);
    float* gin  = (float*)alloc((size_t)TSTEPS * BATCH * G4 * 4);
    float* hA   = (float*)alloc((size_t)LBH * 4);
    float* hB   = (float*)alloc((size_t)LBH * 4);
    float* cS   = (float*)alloc((size_t)LBH * 4);
    unsigned short* wih16  = (unsigned short*)alloc((size_t)NLAYERS * G4 * EDIM * 2);
    unsigned short* wcls16 = (unsigned short*)alloc((size_t)VOCAB * HDIM * 2);
    // total ~71 MB of ws

    // weight conversions (every call; deterministic)
    k_cvt4<<<4096, 256, 0, stream>>>((const float4*)W_ih, (ushort4*)wih16,
                                     (long)NLAYERS * G4 * EDIM / 4);
    k_cvt4<<<8192, 256, 0, stream>>>((const float4*)W_cls, (ushort4*)wcls16,
                                     (long)VOCAB * HDIM / 4);
    // init states
    k_copyf<<<(LBH + 255) / 256, 256, 0, stream>>>(h0, hA, LBH);
    k_copyf<<<(LBH + 255) / 256, 256, 0, stream>>>(c0, cS, LBH);
    // embedding
    k_embed<<<TSTEPS * BATCH, 128, 0, stream>>>(emb, dec, seqF0, seqB0);

    float* curF = seqF0; unsigned short* curB = seqB0;
    float* nxtF = seqF1; unsigned short* nxtB = seqB1;

    for (int l = 0; l < NLAYERS; ++l) {
        // hoisted input GEMM: gin[t*B+b][j] = seq @ W_ih[l]^T + b_ih + b_hh
        k_gemm_bias<<<1024, 256, 0, stream>>>(curB, wih16 + (size_t)l * G4 * EDIM,
                                              b_ih + l * G4, b_hh + l * G4, gin);
        for (int t = 0; t < TSTEPS; ++t) {
            const float* h_in = ((t & 1) ? hB : hA) + (size_t)l * BATCH * HDIM;
            float*       h_out = ((t & 1) ? hA : hB) + (size_t)l * BATCH * HDIM;
            k_lstm_step<<<64, 256, 0, stream>>>(
                gin + (size_t)t * BATCH * G4,
                W_hh + (size_t)l * G4 * HDIM,
                curF + (size_t)t * BATCH * HDIM,
                h_in, h_out,
                cS + (size_t)l * BATCH * HDIM,
                nxtF + (size_t)t * BATCH * HDIM,
                nxtB + (size_t)t * BATCH * HDIM);
        }
        // swap ping-pong sequence buffers
        float* tf = curF; curF = nxtF; nxtF = tf;
        unsigned short* tb = curB; curB = nxtB; nxtB = tb;
    }

    // fused classifier + log_softmax over T (writes all of out[0])
    k_cls<<<250 * 32, 256, 0, stream>>>(curB, wcls16, (float*)d_out);

    // hT (ends in hA after 64 steps), cT
    k_copyf<<<(LBH + 255) / 256, 256, 0, stream>>>(hA, (float*)d_out + BTV, LBH);
    k_copyf<<<(LBH + 255) / 256, 256, 0, stream>>>(cS, (float*)d_out + BTV + LBH, LBH);
}

// Round 2
// 4284.301 us; speedup vs baseline: 4.1883x; 4.1883x over previous
//
#include <hip/hip_runtime.h>
#include <math.h>

#define VOCAB 32000
#define HDIM  512
#define NLAYERS 4
#define BATCH 32
#define TSTEPS 64

typedef __attribute__((ext_vector_type(8))) short bf16x8;
typedef __attribute__((ext_vector_type(4))) float f32x4;

static __device__ __forceinline__ unsigned short f2b(float f) {
    union { float f; unsigned u; } v; v.f = f;
    return (unsigned short)((v.u + 0x7FFFu + ((v.u >> 16) & 1u)) >> 16);
}
static __device__ __forceinline__ float sigf(float x) { return 1.0f / (1.0f + __expf(-x)); }

// packed offset of element (m,k) in a [32 rows][1024 k] bf16 operand stored in
// MFMA-fragment order: [k0=k/32][mi=m/16][lane][8]
static __device__ __forceinline__ int apack_off(int m, int k) {
    int k0 = k >> 5, mi = m >> 4;
    int lane = (m & 15) | (((k >> 3) & 3) << 4);
    return ((k0 * 2 + mi) * 64 + lane) * 8 + (k & 7);
}

// ---------------- grid barrier (device/agent scope, sense via generation) ----------------
static __device__ __forceinline__ void gridbar(unsigned* bar, unsigned nb, unsigned& lgen) {
    __threadfence();   // release: make this block's writes agent-visible
    __syncthreads();
    if (threadIdx.x == 0) {
        unsigned a = __hip_atomic_fetch_add(&bar[0], 1u, __ATOMIC_ACQ_REL, __HIP_MEMORY_SCOPE_AGENT);
        if (a == nb - 1) {
            __hip_atomic_store(&bar[0], 0u, __ATOMIC_RELAXED, __HIP_MEMORY_SCOPE_AGENT);
            __hip_atomic_fetch_add(&bar[1], 1u, __ATOMIC_ACQ_REL, __HIP_MEMORY_SCOPE_AGENT);
        } else {
            while (__hip_atomic_load(&bar[1], __ATOMIC_ACQUIRE, __HIP_MEMORY_SCOPE_AGENT) == lgen) {
                __builtin_amdgcn_s_sleep(1);
            }
        }
        lgen++;
    }
    __syncthreads();
    __threadfence();   // acquire: invalidate caches before reading others' writes
}

// ---------------- weight prep: permuted+packed concat [W_ih | W_hh] -> bf16 ----------------
// wp flat index = ((((l*64+bi)*2+ni)*32+k0)*64+lane)*8+sub
__global__ void k_prep_w(const float* __restrict__ W_ih, const float* __restrict__ W_hh,
                         unsigned short* __restrict__ wp) {
    const int total = NLAYERS * 64 * 2 * 32 * 64 * 8;  // 8388608
    for (int idx = blockIdx.x * blockDim.x + threadIdx.x; idx < total;
         idx += gridDim.x * blockDim.x) {
        int sub = idx & 7, lane = (idx >> 3) & 63, k0 = (idx >> 9) & 31;
        int ni = (idx >> 14) & 1, bi = (idx >> 15) & 63, l = idx >> 21;
        int r = ni * 16 + (lane & 15);
        int k = k0 * 32 + ((lane >> 4) << 3) + sub;
        int j = (r & 3) * 512 + bi * 8 + (r >> 2);   // gate-interleaved row permutation
        float v = (k < 512) ? W_ih[((size_t)l * 2048 + j) * 512 + k]
                            : W_hh[((size_t)l * 2048 + j) * 512 + (k - 512)];
        wp[idx] = f2b(v);
    }
}

__global__ void k_prep_bias(const float* __restrict__ b_ih, const float* __restrict__ b_hh,
                            float* __restrict__ bs) {
    int idx = blockIdx.x * blockDim.x + threadIdx.x;
    if (idx < NLAYERS * 64 * 32) {
        int r = idx & 31, bi = (idx >> 5) & 63, l = idx >> 11;
        int j = (r & 3) * 512 + bi * 8 + (r >> 2);
        bs[idx] = b_ih[l * 2048 + j] + b_hh[l * 2048 + j];
    }
}

// ---------------- fp32 -> bf16 convert (vectorized), for W_cls ----------------
__global__ void k_cvt4(const float4* __restrict__ src, ushort4* __restrict__ dst, long n4) {
    long i = blockIdx.x * (long)blockDim.x + threadIdx.x;
    long stride = (long)gridDim.x * blockDim.x;
    for (; i < n4; i += stride) {
        float4 f = src[i];
        ushort4 u;
        u.x = f2b(f.x); u.y = f2b(f.y); u.z = f2b(f.z); u.w = f2b(f.w);
        dst[i] = u;
    }
}

// ---------------- embedding: fp32 residual seq + packed bf16 seq ----------------
__global__ void k_embed(const float* __restrict__ emb, const int* __restrict__ dec,
                        float* __restrict__ seqF, unsigned short* __restrict__ seqBp) {
    int t = blockIdx.x;
    for (int i = threadIdx.x; i < BATCH * HDIM; i += blockDim.x) {
        int b = i >> 9, e = i & 511;
        int tok = dec[b * TSTEPS + t];
        float v = emb[(size_t)tok * HDIM + e];
        seqF[((size_t)t * BATCH + b) * HDIM + e] = v;
        seqBp[(size_t)t * 16384 + apack_off(b, e)] = f2b(v);
    }
}

// ---------------- persistent LSTM: 4 layers x 64 steps, diagonal pipeline ----------------
// grid = 256 blocks (layer l = blk>>6, n-slice bi = blk&63), 256 threads (4 waves).
// Per block: gates[32b x 32r] = A[32b x 1024] @ Wslice^T via MFMA; W frags in VGPRs.
__global__ __launch_bounds__(256, 1) void k_lstm(
    unsigned short* apack,                    // [4][2][32768] bf16 fragment-packed [inp|h]
    const unsigned short* __restrict__ wpack, // packed weights
    const float* __restrict__ bsum,           // [4*64][32]
    const unsigned short* __restrict__ seqBp, // [64][16384] packed emb
    const float* __restrict__ seqF,           // [64][32][512] fp32 emb (residual for l=0)
    float* outF,                              // [4][2][32][512] fp32 residual stream
    unsigned short* __restrict__ seqOut,      // [64*32][512] final layer out (bf16)
    const float* __restrict__ h0, const float* __restrict__ c0,
    float* __restrict__ outHT, float* __restrict__ outCT,
    unsigned* bar) {
    const int l = blockIdx.x >> 6, bi = blockIdx.x & 63;
    const int wave = threadIdx.x >> 6, lane = threadIdx.x & 63;
    const int mi = wave >> 1, ni = wave & 1;
    const int cb = threadIdx.x >> 3, dsl = threadIdx.x & 7;
    const int d = bi * 8 + dsl;

    __shared__ float sG[32 * 32];

    // stationary W fragments -> registers (128 VGPRs)
    bf16x8 wreg[32];
    {
        const unsigned short* wp = wpack + (size_t)(blockIdx.x * 2 + ni) * 16384;
        #pragma unroll
        for (int k0 = 0; k0 < 32; ++k0)
            wreg[k0] = *(const bf16x8*)(wp + (k0 * 64 + lane) * 8);
    }
    float4 bias = *(const float4*)(bsum + blockIdx.x * 32 + dsl * 4);
    float c = c0[((size_t)l * BATCH + cb) * HDIM + d];

    unsigned short* A0 = apack + (size_t)(l * 2 + 0) * 32768;
    unsigned short* A1 = apack + (size_t)(l * 2 + 1) * 32768;

    // init: h0 -> A(l,0) h-half; layer 0 also stages emb(t=0) inp-half
    A0[apack_off(cb, 512 + d)] = f2b(h0[((size_t)l * BATCH + cb) * HDIM + d]);
    if (l == 0) {
        int idx = bi * 256 + threadIdx.x;
        A0[idx] = seqBp[idx];
    }
    unsigned lgen = 0;
    gridbar(bar, gridDim.x, lgen);

    for (int s = 0; s < TSTEPS + NLAYERS - 1; ++s) {
        int t = s - l;
        bool active = (t >= 0) & (t < TSTEPS);
        if (active) {
            const unsigned short* Ab = (t & 1) ? A1 : A0;
            const unsigned short* abase = Ab + mi * 512 + lane * 8;
            f32x4 acc = {0.f, 0.f, 0.f, 0.f};
            #pragma unroll
            for (int k0 = 0; k0 < 32; ++k0)
                acc = __builtin_amdgcn_mfma_f32_16x16x32_bf16(
                    *(const bf16x8*)(abase + k0 * 1024), wreg[k0], acc, 0, 0, 0);
            int gb = mi * 16 + (lane >> 4) * 4;   // b (C-row)
            int gr = ni * 16 + (lane & 15);       // r (C-col)
            #pragma unroll
            for (int r = 0; r < 4; ++r) sG[(gb + r) * 32 + gr] = acc[r];
        }
        __syncthreads();
        if (active) {
            float4 g4 = *(const float4*)(sG + cb * 32 + dsl * 4);
            float gi = g4.x + bias.x, gf = g4.y + bias.y;
            float gg = g4.z + bias.z, go = g4.w + bias.w;
            float ci = sigf(gf) * c + sigf(gi) * tanhf(gg);
            float hi = sigf(go) * tanhf(ci);
            c = ci;
            float inpf = (l == 0) ? seqF[((size_t)t * BATCH + cb) * HDIM + d]
                                  : outF[(size_t)((l * 2 + (t & 1)) * BATCH + cb) * HDIM + d];
            float o = hi + inpf;

            unsigned short* An = ((t + 1) & 1) ? A1 : A0;
            An[apack_off(cb, 512 + d)] = f2b(hi);     // h -> own next-parity buffer
            if (l < 3) {
                unsigned short* Anx = apack + (size_t)((l + 1) * 2 + (t & 1)) * 32768;
                Anx[apack_off(cb, d)] = f2b(o);       // out -> next layer's inp-half
                outF[(size_t)(((l + 1) * 2 + (t & 1)) * BATCH + cb) * HDIM + d] = o;
            } else {
                seqOut[((size_t)t * BATCH + cb) * HDIM + d] = f2b(o);
            }
            if (t == TSTEPS - 1) {
                outHT[((size_t)l * BATCH + cb) * HDIM + d] = hi;
                outCT[((size_t)l * BATCH + cb) * HDIM + d] = ci;
            }
            if (l == 0 && t + 1 < TSTEPS) {           // stage emb(t+1)
                int idx = bi * 256 + threadIdx.x;
                An[idx] = seqBp[(size_t)(t + 1) * 16384 + idx];
            }
        }
        gridbar(bar, gridDim.x, lgen);
    }
}

// ---------------- fused classifier + log_softmax over T (unchanged, verified) ----------------
__global__ __launch_bounds__(256) void k_cls(
    const unsigned short* __restrict__ A,   // seqOut bf16, rows t*B+b, [.,512]
    const unsigned short* __restrict__ W,   // W_cls bf16 [V][512]
    float* __restrict__ out) {              // [B][T][V]
    int b = blockIdx.x & 31;
    int vt = blockIdx.x >> 5;
    int v0 = vt * 128;
    int wave = threadIdx.x >> 6;
    int lane = threadIdx.x & 63;
    int wn0 = v0 + wave * 32;
    int lm = lane & 15;
    int lk = 8 * (lane >> 4);

    f32x4 acc[4][2];
    #pragma unroll
    for (int i = 0; i < 4; ++i)
        #pragma unroll
        for (int j = 0; j < 2; ++j) acc[i][j] = (f32x4)(0.0f);

    for (int k0 = 0; k0 < HDIM; k0 += 32) {
        bf16x8 a[4], bb[2];
        #pragma unroll
        for (int mi = 0; mi < 4; ++mi) {
            int t = mi * 16 + lm;
            a[mi] = *(const bf16x8*)(A + ((size_t)(t * BATCH + b)) * HDIM + k0 + lk);
        }
        #pragma unroll
        for (int ni = 0; ni < 2; ++ni) {
            int v = wn0 + ni * 16 + lm;
            bb[ni] = *(const bf16x8*)(W + (size_t)v * HDIM + k0 + lk);
        }
        #pragma unroll
        for (int mi = 0; mi < 4; ++mi)
            #pragma unroll
            for (int ni = 0; ni < 2; ++ni)
                acc[mi][ni] = __builtin_amdgcn_mfma_f32_16x16x32_bf16(a[mi], bb[ni], acc[mi][ni], 0, 0, 0);
    }

    #pragma unroll
    for (int ni = 0; ni < 2; ++ni) {
        float m = -1e30f;
        #pragma unroll
        for (int mi = 0; mi < 4; ++mi)
            #pragma unroll
            for (int r = 0; r < 4; ++r) m = fmaxf(m, acc[mi][ni][r]);
        m = fmaxf(m, __shfl_xor(m, 16));
        m = fmaxf(m, __shfl_xor(m, 32));
        float s = 0.f;
        #pragma unroll
        for (int mi = 0; mi < 4; ++mi)
            #pragma unroll
            for (int r = 0; r < 4; ++r) s += expf(acc[mi][ni][r] - m);
        s += __shfl_xor(s, 16);
        s += __shfl_xor(s, 32);
        float logZ = m + logf(s);
        int v = wn0 + ni * 16 + lm;
        #pragma unroll
        for (int mi = 0; mi < 4; ++mi) {
            #pragma unroll
            for (int r = 0; r < 4; ++r) {
                int t = mi * 16 + (lane >> 4) * 4 + r;
                out[((size_t)b * TSTEPS + t) * VOCAB + v] = acc[mi][ni][r] - logZ;
            }
        }
    }
}

extern "C" void kernel_launch(void* const* d_in, const int* in_sizes, int n_in,
                              void* d_out, int out_size, void* d_ws, size_t ws_size,
                              hipStream_t stream) {
    // inputs per setup_inputs(); context (d_in[0]) and b_cls (d_in[10]) unused
    const int*   dec   = (const int*)d_in[1];
    const float* h0    = (const float*)d_in[2];
    const float* c0    = (const float*)d_in[3];
    const float* emb   = (const float*)d_in[4];
    const float* W_ih  = (const float*)d_in[5];
    const float* W_hh  = (const float*)d_in[6];
    const float* b_ih  = (const float*)d_in[7];
    const float* b_hh  = (const float*)d_in[8];
    const float* W_cls = (const float*)d_in[9];

    const int LBH = NLAYERS * BATCH * HDIM;           // 65536
    const size_t BTV = (size_t)BATCH * TSTEPS * VOCAB;

    char* ws = (char*)d_ws;
    size_t off = 0;
    auto alloc = [&](size_t bytes) -> void* {
        void* p = ws + off;
        off = (off + bytes + 255) & ~(size_t)255;
        return p;
    };
    unsigned short* wpack  = (unsigned short*)alloc((size_t)NLAYERS * 64 * 2 * 32 * 64 * 8 * 2);
    float*          bsum   = (float*)alloc((size_t)NLAYERS * 64 * 32 * 4);
    unsigned short* wcls16 = (unsigned short*)alloc((size_t)VOCAB * HDIM * 2);
    float*          seqF   = (float*)alloc((size_t)TSTEPS * BATCH * HDIM * 4);
    unsigned short* seqBp  = (unsigned short*)alloc((size_t)TSTEPS * 16384 * 2);
    unsigned short* apack  = (unsigned short*)alloc((size_t)NLAYERS * 2 * 32768 * 2);
    float*          outF   = (float*)alloc((size_t)NLAYERS * 2 * BATCH * HDIM * 4);
    unsigned short* seqOut = (unsigned short*)alloc((size_t)TSTEPS * BATCH * HDIM * 2);
    unsigned*       bar    = (unsigned*)alloc(256);

    k_prep_w<<<4096, 256, 0, stream>>>(W_ih, W_hh, wpack);
    k_prep_bias<<<32, 256, 0, stream>>>(b_ih, b_hh, bsum);
    k_cvt4<<<8192, 256, 0, stream>>>((const float4*)W_cls, (ushort4*)wcls16,
                                     (long)VOCAB * HDIM / 4);
    k_embed<<<TSTEPS, 256, 0, stream>>>(emb, dec, seqF, seqBp);
    hipMemsetAsync(bar, 0, 256, stream);

    k_lstm<<<256, 256, 0, stream>>>(apack, wpack, bsum, seqBp, seqF, outF, seqOut,
                                    h0, c0,
                                    (float*)d_out + BTV,
                                    (float*)d_out + BTV + LBH,
                                    bar);

    k_cls<<<250 * 32, 256, 0, stream>>>(seqOut, wcls16, (float*)d_out);
}

// Round 3
// 1286.709 us; speedup vs baseline: 13.9457x; 3.3297x over previous
//
#include <hip/hip_runtime.h>
#include <math.h>

#define VOCAB 32000
#define HDIM  512
#define NLAYERS 4
#define BATCH 32
#define TSTEPS 64

typedef __attribute__((ext_vector_type(8))) short bf16x8;
typedef __attribute__((ext_vector_type(4))) float f32x4;

static __device__ __forceinline__ unsigned short f2b(float f) {
    union { float f; unsigned u; } v; v.f = f;
    return (unsigned short)((v.u + 0x7FFFu + ((v.u >> 16) & 1u)) >> 16);
}
static __device__ __forceinline__ float sigf(float x) { return 1.0f / (1.0f + __expf(-x)); }

// packed offset of element (m,k) in a [32 rows][1024 k] bf16 operand stored in
// MFMA-fragment order: [k0=k/32][mi=m/16][lane][8]
static __device__ __forceinline__ int apack_off(int m, int k) {
    int k0 = k >> 5, mi = m >> 4;
    int lane = (m & 15) | (((k >> 3) & 3) << 4);
    return ((k0 * 2 + mi) * 64 + lane) * 8 + (k & 7);
}

// ---------------- weight prep: permuted+packed concat [W_ih | W_hh] -> bf16 ----------------
// wp flat index = ((((l*64+bi)*2+ni)*32+k0)*64+lane)*8+sub   (verified round 2)
__global__ void k_prep_w(const float* __restrict__ W_ih, const float* __restrict__ W_hh,
                         unsigned short* __restrict__ wp) {
    const int total = NLAYERS * 64 * 2 * 32 * 64 * 8;  // 8388608
    for (int idx = blockIdx.x * blockDim.x + threadIdx.x; idx < total;
         idx += gridDim.x * blockDim.x) {
        int sub = idx & 7, lane = (idx >> 3) & 63, k0 = (idx >> 9) & 31;
        int ni = (idx >> 14) & 1, bi = (idx >> 15) & 63, l = idx >> 21;
        int r = ni * 16 + (lane & 15);
        int k = k0 * 32 + ((lane >> 4) << 3) + sub;
        int j = (r & 3) * 512 + bi * 8 + (r >> 2);   // gate-interleaved row permutation
        float v = (k < 512) ? W_ih[((size_t)l * 2048 + j) * 512 + k]
                            : W_hh[((size_t)l * 2048 + j) * 512 + (k - 512)];
        wp[idx] = f2b(v);
    }
}

__global__ void k_prep_bias(const float* __restrict__ b_ih, const float* __restrict__ b_hh,
                            float* __restrict__ bs) {
    int idx = blockIdx.x * blockDim.x + threadIdx.x;
    if (idx < NLAYERS * 64 * 32) {
        int r = idx & 31, bi = (idx >> 5) & 63, l = idx >> 11;
        int j = (r & 3) * 512 + bi * 8 + (r >> 2);
        bs[idx] = b_ih[l * 2048 + j] + b_hh[l * 2048 + j];
    }
}

// ---------------- fp32 -> bf16 convert (vectorized), for W_cls ----------------
__global__ void k_cvt4(const float4* __restrict__ src, ushort4* __restrict__ dst, long n4) {
    long i = blockIdx.x * (long)blockDim.x + threadIdx.x;
    long stride = (long)gridDim.x * blockDim.x;
    for (; i < n4; i += stride) {
        float4 f = src[i];
        ushort4 u;
        u.x = f2b(f.x); u.y = f2b(f.y); u.z = f2b(f.z); u.w = f2b(f.w);
        dst[i] = u;
    }
}

// ---------------- embedding: fp32 residual seq + packed bf16 seq ----------------
__global__ void k_embed(const float* __restrict__ emb, const int* __restrict__ dec,
                        float* __restrict__ seqF, unsigned short* __restrict__ seqBp) {
    int t = blockIdx.x;
    for (int i = threadIdx.x; i < BATCH * HDIM; i += blockDim.x) {
        int b = i >> 9, e = i & 511;
        int tok = dec[b * TSTEPS + t];
        float v = emb[(size_t)tok * HDIM + e];
        seqF[((size_t)t * BATCH + b) * HDIM + e] = v;
        seqBp[(size_t)t * 16384 + apack_off(b, e)] = f2b(v);
    }
}

// ---------------- h0 -> packed h-half of A(l, parity 0) ----------------
__global__ void k_inith(const float* __restrict__ h0, unsigned short* __restrict__ apack) {
    int idx = blockIdx.x * blockDim.x + threadIdx.x;   // 65536
    int l = idx >> 14, b = (idx >> 9) & 31, d = idx & 511;
    apack[(size_t)(l * 2) * 32768 + apack_off(b, 512 + d)] =
        f2b(h0[((size_t)l * BATCH + b) * HDIM + d]);
}

// ---------------- persistent LSTM: producer-consumer pipeline, no global barrier ----------------
// grid = 256 blocks (layer l = blk>>6, slice bi = blk&63), 256 threads (4 waves).
// W slice (64KB) in LDS; A operand staged to LDS each step; gates overlay sA.
__global__ __launch_bounds__(256, 1) void k_lstm(
    unsigned short* apack,                    // [4][2][32768] bf16 fragment-packed [inp|h]
    const unsigned short* __restrict__ wpack, // packed weights
    const float* __restrict__ bsum,           // [4*64][32]
    const unsigned short* __restrict__ seqBp, // [64][16384] packed emb
    const float* __restrict__ seqF,           // [64][32][512] fp32 emb (residual for l=0)
    float* outF,                              // [4][2][32][512] fp32 residual stream
    unsigned short* __restrict__ seqOut,      // [64*32][512] final layer out (bf16)
    const float* __restrict__ c0,
    float* __restrict__ outHT, float* __restrict__ outCT,
    unsigned* arrc) {                         // 4 counters, stride 64 (256B apart)
    const int l = blockIdx.x >> 6, bi = blockIdx.x & 63;
    const int wave = threadIdx.x >> 6, lane = threadIdx.x & 63;
    const int mi = wave >> 1, ni = wave & 1;
    const int cb = threadIdx.x >> 3, dsl = threadIdx.x & 7;
    const int d = bi * 8 + dsl;

    __shared__ short sW[32768];   // 64 KB: W slice, fragment order
    __shared__ short sA[32768];   // 64 KB: A operand staging; first 4KB reused as gates
    float* sG = (float*)sA;

    // stationary W slice -> LDS (once)
    {
        const unsigned short* wp = wpack + (size_t)blockIdx.x * 32768;
        #pragma unroll
        for (int i = 0; i < 16; ++i) {
            int off = (i * 256 + threadIdx.x) * 8;
            *(bf16x8*)(sW + off) = *(const bf16x8*)(wp + off);
        }
    }
    float4 bias = *(const float4*)(bsum + blockIdx.x * 32 + dsl * 4);
    float c = c0[((size_t)l * BATCH + cb) * HDIM + d];

    unsigned short* A0 = apack + (size_t)(l * 2 + 0) * 32768;
    unsigned short* A1 = apack + (size_t)(l * 2 + 1) * 32768;

    for (int t = 0; t < TSTEPS; ++t) {
        // ---- flow control: wait for own h(t-1), upstream inp(t), downstream drain ----
        if (threadIdx.x == 0) {
            if (t > 0)
                while (__hip_atomic_load(&arrc[l * 64], __ATOMIC_RELAXED,
                                         __HIP_MEMORY_SCOPE_AGENT) < (unsigned)(64 * t))
                    __builtin_amdgcn_s_sleep(1);
            if (l > 0)
                while (__hip_atomic_load(&arrc[(l - 1) * 64], __ATOMIC_RELAXED,
                                         __HIP_MEMORY_SCOPE_AGENT) < (unsigned)(64 * (t + 1)))
                    __builtin_amdgcn_s_sleep(1);
            if (l < 3 && t > 0)
                while (__hip_atomic_load(&arrc[(l + 1) * 64], __ATOMIC_RELAXED,
                                         __HIP_MEMORY_SCOPE_AGENT) < (unsigned)(64 * (t - 1)))
                    __builtin_amdgcn_s_sleep(1);
            __builtin_amdgcn_fence(__ATOMIC_ACQUIRE, "agent");   // invalidate L1/L2
        }
        __syncthreads();

        // ---- stage A(l, t&1) -> LDS (dedup; coalesced bf16x8) ----
        const unsigned short* Ab = (t & 1) ? A1 : A0;
        if (l == 0) {
            const unsigned short* sp = seqBp + (size_t)t * 16384;
            #pragma unroll
            for (int i = 0; i < 8; ++i) {          // inp half from packed emb
                int off = (i * 256 + threadIdx.x) * 8;
                *(bf16x8*)(sA + off) = *(const bf16x8*)(sp + off);
            }
            #pragma unroll
            for (int i = 8; i < 16; ++i) {         // h half from global A
                int off = (i * 256 + threadIdx.x) * 8;
                *(bf16x8*)(sA + off) = *(const bf16x8*)(Ab + off);
            }
        } else {
            #pragma unroll
            for (int i = 0; i < 16; ++i) {
                int off = (i * 256 + threadIdx.x) * 8;
                *(bf16x8*)(sA + off) = *(const bf16x8*)(Ab + off);
            }
        }
        __syncthreads();

        // ---- gates = A @ Wslice^T  (each wave one 16x16 tile, K=1024) ----
        f32x4 acc = {0.f, 0.f, 0.f, 0.f};
        const short* abase = sA + mi * 512 + lane * 8;
        const short* wbase = sW + ni * 16384 + lane * 8;
        #pragma unroll
        for (int k0 = 0; k0 < 32; ++k0)
            acc = __builtin_amdgcn_mfma_f32_16x16x32_bf16(
                *(const bf16x8*)(abase + k0 * 1024),
                *(const bf16x8*)(wbase + k0 * 512), acc, 0, 0, 0);
        __syncthreads();   // all sA reads done before sG (aliasing) writes

        int gb = mi * 16 + (lane >> 4) * 4;   // b (C-row)
        int gr = ni * 16 + (lane & 15);       // r (C-col)
        #pragma unroll
        for (int r = 0; r < 4; ++r) sG[(gb + r) * 32 + gr] = acc[r];
        __syncthreads();

        // ---- cell update (thread owns (cb, d)) ----
        float4 g4 = *(const float4*)(sG + cb * 32 + dsl * 4);
        float gi = g4.x + bias.x, gf = g4.y + bias.y;
        float gg = g4.z + bias.z, go = g4.w + bias.w;
        float ci = sigf(gf) * c + sigf(gi) * tanhf(gg);
        float hi = sigf(go) * tanhf(ci);
        c = ci;
        float inpf = (l == 0) ? seqF[((size_t)t * BATCH + cb) * HDIM + d]
                              : outF[(size_t)((l * 2 + (t & 1)) * BATCH + cb) * HDIM + d];
        float o = hi + inpf;

        unsigned short* An = ((t + 1) & 1) ? A1 : A0;
        An[apack_off(cb, 512 + d)] = f2b(hi);        // h -> own next-parity buffer
        if (l < 3) {
            unsigned short* Anx = apack + (size_t)((l + 1) * 2 + (t & 1)) * 32768;
            Anx[apack_off(cb, d)] = f2b(o);          // inp -> downstream, same parity
            outF[(size_t)(((l + 1) * 2 + (t & 1)) * BATCH + cb) * HDIM + d] = o;
        } else {
            seqOut[((size_t)t * BATCH + cb) * HDIM + d] = f2b(o);
        }
        if (t == TSTEPS - 1) {
            outHT[((size_t)l * BATCH + cb) * HDIM + d] = hi;
            outCT[((size_t)l * BATCH + cb) * HDIM + d] = ci;
        }
        __syncthreads();   // drains all threads' vmem stores (vmcnt(0) before s_barrier)
        if (threadIdx.x == 0)
            __hip_atomic_fetch_add(&arrc[l * 64], 1u, __ATOMIC_RELEASE,
                                   __HIP_MEMORY_SCOPE_AGENT);   // wbl2 + arrive
    }
}

// ---------------- fused classifier + log_softmax over T (verified round 1/2) ----------------
__global__ __launch_bounds__(256) void k_cls(
    const unsigned short* __restrict__ A,   // seqOut bf16, rows t*B+b, [.,512]
    const unsigned short* __restrict__ W,   // W_cls bf16 [V][512]
    float* __restrict__ out) {              // [B][T][V]
    int b = blockIdx.x & 31;
    int vt = blockIdx.x >> 5;
    int v0 = vt * 128;
    int wave = threadIdx.x >> 6;
    int lane = threadIdx.x & 63;
    int wn0 = v0 + wave * 32;
    int lm = lane & 15;
    int lk = 8 * (lane >> 4);

    f32x4 acc[4][2];
    #pragma unroll
    for (int i = 0; i < 4; ++i)
        #pragma unroll
        for (int j = 0; j < 2; ++j) acc[i][j] = (f32x4)(0.0f);

    for (int k0 = 0; k0 < HDIM; k0 += 32) {
        bf16x8 a[4], bb[2];
        #pragma unroll
        for (int mi = 0; mi < 4; ++mi) {
            int t = mi * 16 + lm;
            a[mi] = *(const bf16x8*)(A + ((size_t)(t * BATCH + b)) * HDIM + k0 + lk);
        }
        #pragma unroll
        for (int ni = 0; ni < 2; ++ni) {
            int v = wn0 + ni * 16 + lm;
            bb[ni] = *(const bf16x8*)(W + (size_t)v * HDIM + k0 + lk);
        }
        #pragma unroll
        for (int mi = 0; mi < 4; ++mi)
            #pragma unroll
            for (int ni = 0; ni < 2; ++ni)
                acc[mi][ni] = __builtin_amdgcn_mfma_f32_16x16x32_bf16(a[mi], bb[ni], acc[mi][ni], 0, 0, 0);
    }

    #pragma unroll
    for (int ni = 0; ni < 2; ++ni) {
        float m = -1e30f;
        #pragma unroll
        for (int mi = 0; mi < 4; ++mi)
            #pragma unroll
            for (int r = 0; r < 4; ++r) m = fmaxf(m, acc[mi][ni][r]);
        m = fmaxf(m, __shfl_xor(m, 16));
        m = fmaxf(m, __shfl_xor(m, 32));
        float s = 0.f;
        #pragma unroll
        for (int mi = 0; mi < 4; ++mi)
            #pragma unroll
            for (int r = 0; r < 4; ++r) s += expf(acc[mi][ni][r] - m);
        s += __shfl_xor(s, 16);
        s += __shfl_xor(s, 32);
        float logZ = m + logf(s);
        int v = wn0 + ni * 16 + lm;
        #pragma unroll
        for (int mi = 0; mi < 4; ++mi) {
            #pragma unroll
            for (int r = 0; r < 4; ++r) {
                int t = mi * 16 + (lane >> 4) * 4 + r;
                out[((size_t)b * TSTEPS + t) * VOCAB + v] = acc[mi][ni][r] - logZ;
            }
        }
    }
}

extern "C" void kernel_launch(void* const* d_in, const int* in_sizes, int n_in,
                              void* d_out, int out_size, void* d_ws, size_t ws_size,
                              hipStream_t stream) {
    // inputs per setup_inputs(); context (d_in[0]) and b_cls (d_in[10]) unused
    const int*   dec   = (const int*)d_in[1];
    const float* h0    = (const float*)d_in[2];
    const float* c0    = (const float*)d_in[3];
    const float* emb   = (const float*)d_in[4];
    const float* W_ih  = (const float*)d_in[5];
    const float* W_hh  = (const float*)d_in[6];
    const float* b_ih  = (const float*)d_in[7];
    const float* b_hh  = (const float*)d_in[8];
    const float* W_cls = (const float*)d_in[9];

    const int LBH = NLAYERS * BATCH * HDIM;           // 65536
    const size_t BTV = (size_t)BATCH * TSTEPS * VOCAB;

    char* ws = (char*)d_ws;
    size_t off = 0;
    auto alloc = [&](size_t bytes) -> void* {
        void* p = ws + off;
        off = (off + bytes + 255) & ~(size_t)255;
        return p;
    };
    unsigned short* wpack  = (unsigned short*)alloc((size_t)NLAYERS * 64 * 2 * 32 * 64 * 8 * 2);
    float*          bsum   = (float*)alloc((size_t)NLAYERS * 64 * 32 * 4);
    unsigned short* wcls16 = (unsigned short*)alloc((size_t)VOCAB * HDIM * 2);
    float*          seqF   = (float*)alloc((size_t)TSTEPS * BATCH * HDIM * 4);
    unsigned short* seqBp  = (unsigned short*)alloc((size_t)TSTEPS * 16384 * 2);
    unsigned short* apack  = (unsigned short*)alloc((size_t)NLAYERS * 2 * 32768 * 2);
    float*          outF   = (float*)alloc((size_t)NLAYERS * 2 * BATCH * HDIM * 4);
    unsigned short* seqOut = (unsigned short*)alloc((size_t)TSTEPS * BATCH * HDIM * 2);
    unsigned*       arrc   = (unsigned*)alloc(1024);

    k_prep_w<<<4096, 256, 0, stream>>>(W_ih, W_hh, wpack);
    k_prep_bias<<<32, 256, 0, stream>>>(b_ih, b_hh, bsum);
    k_cvt4<<<8192, 256, 0, stream>>>((const float4*)W_cls, (ushort4*)wcls16,
                                     (long)VOCAB * HDIM / 4);
    k_embed<<<TSTEPS, 256, 0, stream>>>(emb, dec, seqF, seqBp);
    k_inith<<<256, 256, 0, stream>>>(h0, apack);
    hipMemsetAsync(arrc, 0, 1024, stream);

    k_lstm<<<256, 256, 0, stream>>>(apack, wpack, bsum, seqBp, seqF, outF, seqOut,
                                    c0,
                                    (float*)d_out + BTV,
                                    (float*)d_out + BTV + LBH,
                                    arrc);

    k_cls<<<250 * 32, 256, 0, stream>>>(seqOut, wcls16, (float*)d_out);
}

// Round 4
// 1151.339 us; speedup vs baseline: 15.5853x; 1.1176x over previous
//
#include <hip/hip_runtime.h>
#include <math.h>

#define VOCAB 32000
#define HDIM  512
#define NLAYERS 4
#define BATCH 32
#define TSTEPS 64
typedef unsigned long long ULL;

typedef __attribute__((ext_vector_type(8))) short bf16x8;
typedef __attribute__((ext_vector_type(4))) float f32x4;

static __device__ __forceinline__ unsigned short f2b(float f) {
    union { float f; unsigned u; } v; v.f = f;
    return (unsigned short)((v.u + 0x7FFFu + ((v.u >> 16) & 1u)) >> 16);
}
static __device__ __forceinline__ float sigf(float x) { return 1.0f / (1.0f + __expf(-x)); }

// packed offset of element (m,k) in a [32 rows][1024 k] bf16 operand stored in
// MFMA-fragment order: [k0=k/32][mi=m/16][lane][8]
static __device__ __forceinline__ int apack_off(int m, int k) {
    int k0 = k >> 5, mi = m >> 4;
    int lane = (m & 15) | (((k >> 3) & 3) << 4);
    return ((k0 * 2 + mi) * 64 + lane) * 8 + (k & 7);
}

// ---------------- weight prep (verified round 2/3) ----------------
__global__ void k_prep_w(const float* __restrict__ W_ih, const float* __restrict__ W_hh,
                         unsigned short* __restrict__ wp) {
    const int total = NLAYERS * 64 * 2 * 32 * 64 * 8;  // 8388608
    for (int idx = blockIdx.x * blockDim.x + threadIdx.x; idx < total;
         idx += gridDim.x * blockDim.x) {
        int sub = idx & 7, lane = (idx >> 3) & 63, k0 = (idx >> 9) & 31;
        int ni = (idx >> 14) & 1, bi = (idx >> 15) & 63, l = idx >> 21;
        int r = ni * 16 + (lane & 15);
        int k = k0 * 32 + ((lane >> 4) << 3) + sub;
        int j = (r & 3) * 512 + bi * 8 + (r >> 2);
        float v = (k < 512) ? W_ih[((size_t)l * 2048 + j) * 512 + k]
                            : W_hh[((size_t)l * 2048 + j) * 512 + (k - 512)];
        wp[idx] = f2b(v);
    }
}

__global__ void k_prep_bias(const float* __restrict__ b_ih, const float* __restrict__ b_hh,
                            float* __restrict__ bs) {
    int idx = blockIdx.x * blockDim.x + threadIdx.x;
    if (idx < NLAYERS * 64 * 32) {
        int r = idx & 31, bi = (idx >> 5) & 63, l = idx >> 11;
        int j = (r & 3) * 512 + bi * 8 + (r >> 2);
        bs[idx] = b_ih[l * 2048 + j] + b_hh[l * 2048 + j];
    }
}

__global__ void k_cvt4(const float4* __restrict__ src, ushort4* __restrict__ dst, long n4) {
    long i = blockIdx.x * (long)blockDim.x + threadIdx.x;
    long stride = (long)gridDim.x * blockDim.x;
    for (; i < n4; i += stride) {
        float4 f = src[i];
        ushort4 u;
        u.x = f2b(f.x); u.y = f2b(f.y); u.z = f2b(f.z); u.w = f2b(f.w);
        dst[i] = u;
    }
}

__global__ void k_embed(const float* __restrict__ emb, const int* __restrict__ dec,
                        float* __restrict__ seqF, unsigned short* __restrict__ seqBp) {
    int t = blockIdx.x;
    for (int i = threadIdx.x; i < BATCH * HDIM; i += blockDim.x) {
        int b = i >> 9, e = i & 511;
        int tok = dec[b * TSTEPS + t];
        float v = emb[(size_t)tok * HDIM + e];
        seqF[((size_t)t * BATCH + b) * HDIM + e] = v;
        seqBp[(size_t)t * 16384 + apack_off(b, e)] = f2b(v);
    }
}

__global__ void k_inith(const float* __restrict__ h0, unsigned short* __restrict__ apack) {
    int idx = blockIdx.x * blockDim.x + threadIdx.x;   // 65536
    int l = idx >> 14, b = (idx >> 9) & 31, d = idx & 511;
    apack[(size_t)(l * 2) * 32768 + apack_off(b, 512 + d)] =
        f2b(h0[((size_t)l * BATCH + b) * HDIM + d]);
}

// ---------------- persistent LSTM: fence-free producer/consumer pipeline ----------------
// 256 blocks (layer l = blk>>6, slice bi = blk&63) x 256 threads.
// Consumers read cross-block data via agent-scope relaxed atomic loads (sc-bypass,
// coherence point) -> NO acquire fence / L2 invalidate. Producers: cached stores +
// one RELEASE fetch_add per step (waitcnt + wbl2 flushes ~2.5KB dirty).
__global__ __launch_bounds__(256, 1) void k_lstm(
    unsigned short* apack,                    // [4][2][32768] bf16 fragment-packed [inp|h]
    const unsigned short* __restrict__ wpack,
    const float* __restrict__ bsum,
    const unsigned short* __restrict__ seqBp, // [64][16384] packed emb (read-only, cached)
    const float* __restrict__ seqF,           // [64][32][512] fp32 emb (read-only, cached)
    float* outF,                              // [4][2][32][512] fp32 residual exchange
    unsigned short* __restrict__ seqOut,      // [64*32][512] final layer out (bf16)
    const float* __restrict__ c0,
    float* __restrict__ outHT, float* __restrict__ outCT,
    unsigned* arrc) {                         // 4 counters, stride 1024 u32 (4KB apart)
    const int l = blockIdx.x >> 6, bi = blockIdx.x & 63;
    const int wave = threadIdx.x >> 6, lane = threadIdx.x & 63;
    const int mi = wave >> 1, ni = wave & 1;
    const int cb = threadIdx.x >> 3, dsl = threadIdx.x & 7;
    const int d = bi * 8 + dsl;

    __shared__ short sW[32768];    // 64 KB W slice
    __shared__ short sA[32768];    // 64 KB A staging
    __shared__ float sG[1024];     //  4 KB gates
    __shared__ short sHexH[512];   //  1 KB h export repack
    __shared__ short sHexO[512];   //  1 KB o export repack

    {   // stationary W slice -> LDS (cached reads, once)
        const unsigned short* wp = wpack + (size_t)blockIdx.x * 32768;
        #pragma unroll
        for (int i = 0; i < 16; ++i) {
            int off = (i * 256 + threadIdx.x) * 8;
            *(bf16x8*)(sW + off) = *(const bf16x8*)(wp + off);
        }
    }
    float4 bias = *(const float4*)(bsum + blockIdx.x * 32 + dsl * 4);
    float c = c0[((size_t)l * BATCH + cb) * HDIM + d];

    unsigned short* A0 = apack + (size_t)(l * 2 + 0) * 32768;
    unsigned short* A1 = apack + (size_t)(l * 2 + 1) * 32768;

    for (int t = 0; t < TSTEPS; ++t) {
        // ---- flow control: 3 conditions polled concurrently by lanes 0/1/2 ----
        if (threadIdx.x == 0 && t > 0)
            while (__hip_atomic_load(&arrc[l * 1024], __ATOMIC_RELAXED,
                                     __HIP_MEMORY_SCOPE_AGENT) < (unsigned)(64 * t))
                __builtin_amdgcn_s_sleep(2);
        if (threadIdx.x == 1 && l > 0)
            while (__hip_atomic_load(&arrc[(l - 1) * 1024], __ATOMIC_RELAXED,
                                     __HIP_MEMORY_SCOPE_AGENT) < (unsigned)(64 * (t + 1)))
                __builtin_amdgcn_s_sleep(2);
        if (threadIdx.x == 2 && l < 3 && t > 0)
            while (__hip_atomic_load(&arrc[(l + 1) * 1024], __ATOMIC_RELAXED,
                                     __HIP_MEMORY_SCOPE_AGENT) < (unsigned)(64 * (t - 1)))
                __builtin_amdgcn_s_sleep(2);
        __syncthreads();

        // ---- residual input: fp32, issued early to hide latency ----
        float inpf;
        if (l == 0) inpf = seqF[((size_t)t * BATCH + cb) * HDIM + d];           // cached
        else inpf = __hip_atomic_load(&outF[(size_t)((l * 2 + (t & 1)) * BATCH + cb) * HDIM + d],
                                      __ATOMIC_RELAXED, __HIP_MEMORY_SCOPE_AGENT);

        // ---- stage A(l, t&1) -> LDS via coherence-point loads (batched) ----
        const unsigned short* Ab = (t & 1) ? A1 : A0;
        const ULL* Abu = (const ULL*)Ab;
        ULL* sAu = (ULL*)sA;
        if (l == 0) {
            const unsigned short* sp = seqBp + (size_t)t * 16384;
            #pragma unroll
            for (int i = 0; i < 8; ++i) {          // inp half: cached (read-only emb)
                int off = (i * 256 + threadIdx.x) * 8;
                *(bf16x8*)(sA + off) = *(const bf16x8*)(sp + off);
            }
            ULL tmp[16];
            #pragma unroll
            for (int i = 0; i < 16; ++i)           // h half: bypass loads, batched
                tmp[i] = __hip_atomic_load(&Abu[(16 + i) * 256 + threadIdx.x],
                                           __ATOMIC_RELAXED, __HIP_MEMORY_SCOPE_AGENT);
            #pragma unroll
            for (int i = 0; i < 16; ++i)
                sAu[(16 + i) * 256 + threadIdx.x] = tmp[i];
        } else {
            ULL tmp[32];
            #pragma unroll
            for (int i = 0; i < 32; ++i)
                tmp[i] = __hip_atomic_load(&Abu[i * 256 + threadIdx.x],
                                           __ATOMIC_RELAXED, __HIP_MEMORY_SCOPE_AGENT);
            #pragma unroll
            for (int i = 0; i < 32; ++i)
                sAu[i * 256 + threadIdx.x] = tmp[i];
        }
        __syncthreads();

        // ---- gates = A @ Wslice^T (each wave one 16x16 tile, K=1024) ----
        f32x4 acc = {0.f, 0.f, 0.f, 0.f};
        const short* abase = sA + mi * 512 + lane * 8;
        const short* wbase = sW + ni * 16384 + lane * 8;
        #pragma unroll
        for (int k0 = 0; k0 < 32; ++k0)
            acc = __builtin_amdgcn_mfma_f32_16x16x32_bf16(
                *(const bf16x8*)(abase + k0 * 1024),
                *(const bf16x8*)(wbase + k0 * 512), acc, 0, 0, 0);

        int gb = mi * 16 + (lane >> 4) * 4;
        int gr = ni * 16 + (lane & 15);
        #pragma unroll
        for (int r = 0; r < 4; ++r) sG[(gb + r) * 32 + gr] = acc[r];
        __syncthreads();

        // ---- cell update (thread owns (cb, d)) ----
        float4 g4 = *(const float4*)(sG + cb * 32 + dsl * 4);
        float gi = g4.x + bias.x, gf = g4.y + bias.y;
        float gg = g4.z + bias.z, go = g4.w + bias.w;
        float ci = sigf(gf) * c + sigf(gi) * tanhf(gg);
        float hi = sigf(go) * tanhf(ci);
        c = ci;
        float o = hi + inpf;

        sHexH[cb * 8 + dsl] = f2b(hi);
        sHexO[cb * 8 + dsl] = f2b(o);
        if (l < 3)    // fp32 residual side-channel (cached store; flushed by release)
            outF[(size_t)(((l + 1) * 2 + (t & 1)) * BATCH + cb) * HDIM + d] = o;
        if (t == TSTEPS - 1) {
            outHT[((size_t)l * BATCH + cb) * HDIM + d] = hi;
            outCT[((size_t)l * BATCH + cb) * HDIM + d] = ci;
        }
        __syncthreads();

        // ---- export: coalesced 16B chunks (disjoint 256B regions per block) ----
        unsigned short* An = ((t + 1) & 1) ? A1 : A0;
        int i = threadIdx.x & 63, cbe = i >> 1, jh = i & 1;
        int lanecode = ((cbe & 15) | ((bi & 3) << 4)) * 2 + jh;
        if (threadIdx.x < 64) {
            int hoff = ((16 + (bi >> 2)) * 2 + (cbe >> 4)) * 128 + lanecode;
            ((ULL*)An)[hoff] = ((const ULL*)sHexH)[i];
        } else if (threadIdx.x < 128) {
            if (l < 3) {
                unsigned short* Anx = apack + (size_t)((l + 1) * 2 + (t & 1)) * 32768;
                int ooff = ((bi >> 2) * 2 + (cbe >> 4)) * 128 + lanecode;
                ((ULL*)Anx)[ooff] = ((const ULL*)sHexO)[i];
            } else {
                ((ULL*)seqOut)[(t * 32 + cbe) * 128 + bi * 2 + jh] = ((const ULL*)sHexO)[i];
            }
        }
        __syncthreads();   // drains all waves' stores (vmcnt0 before s_barrier)

        if (threadIdx.x == 0)   // release: waitcnt + wbl2 (flush dirty) + arrive
            __hip_atomic_fetch_add(&arrc[l * 1024], 1u, __ATOMIC_RELEASE,
                                   __HIP_MEMORY_SCOPE_AGENT);
    }
}

// ---------------- fused classifier + log_softmax over T (verified) ----------------
__global__ __launch_bounds__(256) void k_cls(
    const unsigned short* __restrict__ A,   // seqOut bf16, rows t*B+b, [.,512]
    const unsigned short* __restrict__ W,   // W_cls bf16 [V][512]
    float* __restrict__ out) {              // [B][T][V]
    int b = blockIdx.x & 31;
    int vt = blockIdx.x >> 5;
    int v0 = vt * 128;
    int wave = threadIdx.x >> 6;
    int lane = threadIdx.x & 63;
    int wn0 = v0 + wave * 32;
    int lm = lane & 15;
    int lk = 8 * (lane >> 4);

    f32x4 acc[4][2];
    #pragma unroll
    for (int i = 0; i < 4; ++i)
        #pragma unroll
        for (int j = 0; j < 2; ++j) acc[i][j] = (f32x4)(0.0f);

    for (int k0 = 0; k0 < HDIM; k0 += 32) {
        bf16x8 a[4], bb[2];
        #pragma unroll
        for (int mi = 0; mi < 4; ++mi) {
            int t = mi * 16 + lm;
            a[mi] = *(const bf16x8*)(A + ((size_t)(t * BATCH + b)) * HDIM + k0 + lk);
        }
        #pragma unroll
        for (int ni = 0; ni < 2; ++ni) {
            int v = wn0 + ni * 16 + lm;
            bb[ni] = *(const bf16x8*)(W + (size_t)v * HDIM + k0 + lk);
        }
        #pragma unroll
        for (int mi = 0; mi < 4; ++mi)
            #pragma unroll
            for (int ni = 0; ni < 2; ++ni)
                acc[mi][ni] = __builtin_amdgcn_mfma_f32_16x16x32_bf16(a[mi], bb[ni], acc[mi][ni], 0, 0, 0);
    }

    #pragma unroll
    for (int ni = 0; ni < 2; ++ni) {
        float m = -1e30f;
        #pragma unroll
        for (int mi = 0; mi < 4; ++mi)
            #pragma unroll
            for (int r = 0; r < 4; ++r) m = fmaxf(m, acc[mi][ni][r]);
        m = fmaxf(m, __shfl_xor(m, 16));
        m = fmaxf(m, __shfl_xor(m, 32));
        float s = 0.f;
        #pragma unroll
        for (int mi = 0; mi < 4; ++mi)
            #pragma unroll
            for (int r = 0; r < 4; ++r) s += expf(acc[mi][ni][r] - m);
        s += __shfl_xor(s, 16);
        s += __shfl_xor(s, 32);
        float logZ = m + logf(s);
        int v = wn0 + ni * 16 + lm;
        #pragma unroll
        for (int mi = 0; mi < 4; ++mi) {
            #pragma unroll
            for (int r = 0; r < 4; ++r) {
                int t = mi * 16 + (lane >> 4) * 4 + r;
                out[((size_t)b * TSTEPS + t) * VOCAB + v] = acc[mi][ni][r] - logZ;
            }
        }
    }
}

extern "C" void kernel_launch(void* const* d_in, const int* in_sizes, int n_in,
                              void* d_out, int out_size, void* d_ws, size_t ws_size,
                              hipStream_t stream) {
    const int*   dec   = (const int*)d_in[1];
    const float* h0    = (const float*)d_in[2];
    const float* c0    = (const float*)d_in[3];
    const float* emb   = (const float*)d_in[4];
    const float* W_ih  = (const float*)d_in[5];
    const float* W_hh  = (const float*)d_in[6];
    const float* b_ih  = (const float*)d_in[7];
    const float* b_hh  = (const float*)d_in[8];
    const float* W_cls = (const float*)d_in[9];

    const int LBH = NLAYERS * BATCH * HDIM;           // 65536
    const size_t BTV = (size_t)BATCH * TSTEPS * VOCAB;

    char* ws = (char*)d_ws;
    size_t off = 0;
    auto alloc = [&](size_t bytes) -> void* {
        void* p = ws + off;
        off = (off + bytes + 255) & ~(size_t)255;
        return p;
    };
    unsigned short* wpack  = (unsigned short*)alloc((size_t)NLAYERS * 64 * 2 * 32 * 64 * 8 * 2);
    float*          bsum   = (float*)alloc((size_t)NLAYERS * 64 * 32 * 4);
    unsigned short* wcls16 = (unsigned short*)alloc((size_t)VOCAB * HDIM * 2);
    float*          seqF   = (float*)alloc((size_t)TSTEPS * BATCH * HDIM * 4);
    unsigned short* seqBp  = (unsigned short*)alloc((size_t)TSTEPS * 16384 * 2);
    unsigned short* apack  = (unsigned short*)alloc((size_t)NLAYERS * 2 * 32768 * 2);
    float*          outF   = (float*)alloc((size_t)NLAYERS * 2 * BATCH * HDIM * 4);
    unsigned short* seqOut = (unsigned short*)alloc((size_t)TSTEPS * BATCH * HDIM * 2);
    unsigned*       arrc   = (unsigned*)alloc(16384);

    k_prep_w<<<4096, 256, 0, stream>>>(W_ih, W_hh, wpack);
    k_prep_bias<<<32, 256, 0, stream>>>(b_ih, b_hh, bsum);
    k_cvt4<<<8192, 256, 0, stream>>>((const float4*)W_cls, (ushort4*)wcls16,
                                     (long)VOCAB * HDIM / 4);
    k_embed<<<TSTEPS, 256, 0, stream>>>(emb, dec, seqF, seqBp);
    k_inith<<<256, 256, 0, stream>>>(h0, apack);
    hipMemsetAsync(arrc, 0, 16384, stream);

    k_lstm<<<256, 256, 0, stream>>>(apack, wpack, bsum, seqBp, seqF, outF, seqOut,
                                    c0,
                                    (float*)d_out + BTV,
                                    (float*)d_out + BTV + LBH,
                                    arrc);

    k_cls<<<250 * 32, 256, 0, stream>>>(seqOut, wcls16, (float*)d_out);
}